// Round 7
// baseline (108.921 us; speedup 1.0000x reference)
//
#include <hip/hip_runtime.h>

#define NB 4
#define NN 256
#define ND 512
#define NITER 10

typedef _Float16 half_t;
typedef __attribute__((ext_vector_type(8))) unsigned short ushort8v;
typedef __attribute__((ext_vector_type(8))) _Float16 half8v;
typedef __attribute__((ext_vector_type(2))) _Float16 half2v;

__device__ __forceinline__ unsigned short f2bf(float x) {
  unsigned u = __float_as_uint(x);
  u += 0x7fffu + ((u >> 16) & 1u);   // round-to-nearest-even
  return (unsigned short)(u >> 16);
}
__device__ __forceinline__ float bf2f(unsigned short h) {
  return __uint_as_float(((unsigned)h) << 16);
}

// ---------------------------------------------------------------- softmax ---
// one block per row; 2048 rows total (p_s then p_t). fp16 output.
// Block 0 also zeroes d_out (stream-ordered before sink_k's atomicAdd).
__global__ __launch_bounds__(256) void softmax_k(const float* __restrict__ ys,
                                                 const float* __restrict__ yt,
                                                 half_t* __restrict__ ps,
                                                 half_t* __restrict__ pt,
                                                 float* __restrict__ out) {
  int bb = blockIdx.x;
  if (bb == 0 && threadIdx.x == 0) out[0] = 0.0f;
  const float* src = (bb < NB * NN) ? ys : yt;
  half_t* dst      = (bb < NB * NN) ? ps : pt;
  int row = bb & (NB * NN - 1);
  const float* rp = src + (size_t)row * ND;
  half_t* wp = dst + (size_t)row * ND;
  int t = threadIdx.x;
  float a = rp[t];
  float b = rp[t + 256];
  float m = fmaxf(a, b);
  #pragma unroll
  for (int s = 1; s < 64; s <<= 1) m = fmaxf(m, __shfl_xor(m, s));
  __shared__ float red[4];
  int wid = t >> 6;
  if ((t & 63) == 0) red[wid] = m;
  __syncthreads();
  m = fmaxf(fmaxf(red[0], red[1]), fmaxf(red[2], red[3]));
  float e0 = expf((a - m) * 0.5f);   // softmax(y/2)
  float e1 = expf((b - m) * 0.5f);
  float ssum = e0 + e1;
  #pragma unroll
  for (int s = 1; s < 64; s <<= 1) ssum += __shfl_xor(ssum, s);
  __syncthreads();
  if ((t & 63) == 0) red[wid] = ssum;
  __syncthreads();
  ssum = red[0] + red[1] + red[2] + red[3];
  float inv = 1.0f / ssum;
  wp[t]       = (half_t)(e0 * inv);
  wp[t + 256] = (half_t)(e1 * inv);
}

// ------------------------------------------------------------ cost matrix ---
// W[b][i][j] = sum_d |ps[b,i,d] - pt[b,j,d]|, fp16 in / fp16 out.
// 32x32 tile per WG, full D staged in LDS as fp16 (32KB/side).
// LDS-issue-bound (~12 cyc/b128); layout/instr count already near floor for
// the 2x2 micro-tile (reads-per-output minimized at 256 CUs' parallelism).
__global__ __launch_bounds__(256) void cost_k(const half_t* __restrict__ ps,
                                              const half_t* __restrict__ pt,
                                              half_t* __restrict__ W) {
  __shared__ half_t xs[32 * 512];   // 32 KiB
  __shared__ half_t ysh[32 * 512];  // 32 KiB
  int b  = blockIdx.z;
  int It = blockIdx.y * 32;
  int Jt = blockIdx.x * 32;
  int t = threadIdx.x;
  const half8v* xg = reinterpret_cast<const half8v*>(ps + ((size_t)b * NN + It) * ND);
  const half8v* yg = reinterpret_cast<const half8v*>(pt + ((size_t)b * NN + Jt) * ND);
  half8v* xsv = reinterpret_cast<half8v*>(xs);
  half8v* ysv = reinterpret_cast<half8v*>(ysh);
  #pragma unroll
  for (int s = 0; s < 8; ++s) {
    int qidx = s * 256 + t;        // quad index 0..2047 (= r*64 + q)
    int r = qidx >> 6;
    int q = qidx & 63;
    int rot = (r + (r >> 3)) & 7;
    int dst = r * 64 + ((q + rot) & 63);
    xsv[dst] = xg[qidx];
    ysv[dst] = yg[qidx];
  }
  __syncthreads();
  int tx = t & 15, ty = t >> 4;
  int i0 = 2 * ty, j0 = 2 * tx;
  int rx0 = (i0 + (i0 >> 3)) & 7;
  int rx1 = ((i0 + 1) + ((i0 + 1) >> 3)) & 7;
  int ry0 = (j0 + (j0 >> 3)) & 7;
  int ry1 = ((j0 + 1) + ((j0 + 1) >> 3)) & 7;
  float a00 = 0.f, a01 = 0.f, a10 = 0.f, a11 = 0.f;
  #pragma unroll 4
  for (int qq = 0; qq < 64; ++qq) {
    half8v x0 = xsv[i0 * 64 + ((qq + rx0) & 63)];
    half8v x1 = xsv[(i0 + 1) * 64 + ((qq + rx1) & 63)];
    half8v y0 = ysv[j0 * 64 + ((qq + ry0) & 63)];
    half8v y1 = ysv[(j0 + 1) * 64 + ((qq + ry1) & 63)];
    #pragma unroll
    for (int e = 0; e < 8; ++e) {
      float xf0 = (float)x0[e], xf1 = (float)x1[e];
      float yf0 = (float)y0[e], yf1 = (float)y1[e];
      a00 += fabsf(xf0 - yf0);
      a01 += fabsf(xf0 - yf1);
      a10 += fabsf(xf1 - yf0);
      a11 += fabsf(xf1 - yf1);
    }
  }
  half_t* wb = W + ((size_t)b * NN + It + i0) * NN + Jt + j0;
  half2v w0; w0[0] = (half_t)a00; w0[1] = (half_t)a01;
  half2v w1; w1[0] = (half_t)a10; w1[1] = (half_t)a11;
  *reinterpret_cast<half2v*>(wb)      = w0;
  *reinterpret_cast<half2v*>(wb + NN) = w1;
}

// ---------------------------------------------------------------- sinkhorn ---
// P = diag(u) K diag(v); K bf16 in LDS, 8-elem XOR swizzle pj = j ^ ((i&7)<<3).
// One WG per batch, 1024 threads. u/v canonical fp32; bf16 shadow copies
// (usb/vsb) feed the matvec reads -> halves broadcast LDS instructions.
__global__ __launch_bounds__(1024) void sink_k(const half_t* __restrict__ Wg,
                                               float* __restrict__ out) {
  __shared__ __align__(16) unsigned short Kl[NN * NN];  // 128 KiB
  __shared__ __align__(16) float u[NN];
  __shared__ __align__(16) float v[NN];
  __shared__ __align__(16) unsigned short usb[NN];      // bf16 shadow of u
  __shared__ __align__(16) unsigned short vsb[NN];      // bf16 shadow of v
  __shared__ __align__(16) float scr[16 * NN];          // 16 KiB
  int b = blockIdx.x;
  int t = threadIdx.x;
  const half8v* W8 = reinterpret_cast<const half8v*>(Wg + (size_t)b * NN * NN);

  // build K = exp(-min(W,10)/0.1) + 1e-8  (bf16)
  #pragma unroll
  for (int s = 0; s < 8; ++s) {
    int q8 = s * 1024 + t;       // 8-elem group index 0..8191
    int e = q8 * 8;
    int i = e >> 8;
    int j = e & 255;
    half8v w8 = W8[q8];
    ushort8v kk;
    #pragma unroll
    for (int r = 0; r < 8; ++r) {
      float kf = __expf(fminf((float)w8[r], 10.0f) * -10.0f) + 1e-8f;
      kk[r] = f2bf(kf);
    }
    *reinterpret_cast<ushort8v*>(&Kl[i * 256 + (j ^ ((i & 7) << 3))]) = kk;
  }
  if (t < NN) {
    u[t] = 1.0f; v[t] = 1.0f;
    usb[t] = 0x3F80u; vsb[t] = 0x3F80u;   // bf16(1.0)
  }
  __syncthreads();

  for (int it = 0; it < NITER; ++it) {
    // ---- row pass: r_i = sum_j K[i][j] v[j]   (v read as bf16x8, 1 bcast/chunk)
    {
      int i = t & 255, c = t >> 8;            // c wave-uniform (4 chunks of 64 j)
      const int rowb = i * 256;
      const int sw = (i & 7) << 3;
      float acc = 0.0f;
      #pragma unroll
      for (int q = 0; q < 8; ++q) {
        int j0 = c * 64 + q * 8;
        ushort8v v8 = *reinterpret_cast<const ushort8v*>(&vsb[j0]);        // bcast
        ushort8v k8 = *reinterpret_cast<const ushort8v*>(&Kl[rowb + (j0 ^ sw)]);
        acc += bf2f(k8[0]) * bf2f(v8[0]) + bf2f(k8[1]) * bf2f(v8[1]) +
               bf2f(k8[2]) * bf2f(v8[2]) + bf2f(k8[3]) * bf2f(v8[3]) +
               bf2f(k8[4]) * bf2f(v8[4]) + bf2f(k8[5]) * bf2f(v8[5]) +
               bf2f(k8[6]) * bf2f(v8[6]) + bf2f(k8[7]) * bf2f(v8[7]);
      }
      scr[c * 256 + i] = acc;
    }
    __syncthreads();
    if (t < NN) {
      float r = scr[t] + scr[256 + t] + scr[512 + t] + scr[768 + t];
      float uo = u[t];
      float un = uo / fmaxf(uo * r, 1e-8f);
      u[t] = un;
      usb[t] = f2bf(un);
    }
    __syncthreads();
    // ---- col pass: c_j = sum_i K[i][j] u[i];  4 cols/thread, u as bf16x8 bcasts
    {
      int j4 = t & 63, c = t >> 6;            // c in 0..15, wave-uniform
      int jc = 4 * j4;
      ushort8v ua = *reinterpret_cast<const ushort8v*>(&usb[c * 16]);      // bcast
      ushort8v uc = *reinterpret_cast<const ushort8v*>(&usb[c * 16 + 8]);  // bcast
      float acc0 = 0.f, acc1 = 0.f, acc2 = 0.f, acc3 = 0.f;
      #pragma unroll
      for (int q4 = 0; q4 < 4; ++q4) {
        #pragma unroll
        for (int r = 0; r < 4; ++r) {
          int idx = q4 * 4 + r;               // 0..15, compile-time after unroll
          int i = c * 16 + idx;
          float uf = bf2f(idx < 8 ? ua[idx] : uc[idx - 8]);
          ushort4 k4 = *reinterpret_cast<const ushort4*>(&Kl[i * 256 + (jc ^ ((i & 7) << 3))]);
          acc0 += bf2f(k4.x) * uf; acc1 += bf2f(k4.y) * uf;
          acc2 += bf2f(k4.z) * uf; acc3 += bf2f(k4.w) * uf;
        }
      }
      *reinterpret_cast<float4*>(&scr[c * 256 + jc]) = make_float4(acc0, acc1, acc2, acc3);
    }
    __syncthreads();
    if (t < NN) {
      float s0 = 0.0f;
      #pragma unroll
      for (int c = 0; c < 16; ++c) s0 += scr[c * 256 + t];
      float vo = v[t];
      float vn = vo / fmaxf(vo * s0, 1e-8f);
      v[t] = vn;
      vsb[t] = f2bf(vn);
    }
    __syncthreads();
  }

  // ---- loss = sum_ij u_i K_ij v_j W_ij  (W unclipped fp16; u,v fp32)
  float acc = 0.0f;
  #pragma unroll
  for (int s = 0; s < 8; ++s) {
    int q8 = s * 1024 + t;
    int e = q8 * 8;
    int i = e >> 8;
    int j = e & 255;
    half8v w8 = W8[q8];
    ushort8v k8 = *reinterpret_cast<const ushort8v*>(&Kl[i * 256 + (j ^ ((i & 7) << 3))]);
    float ui = u[i];
    float4 v0 = *reinterpret_cast<const float4*>(&v[j]);
    float4 v1 = *reinterpret_cast<const float4*>(&v[j + 4]);
    acc += ui * (bf2f(k8[0]) * v0.x * (float)w8[0] + bf2f(k8[1]) * v0.y * (float)w8[1] +
                 bf2f(k8[2]) * v0.z * (float)w8[2] + bf2f(k8[3]) * v0.w * (float)w8[3] +
                 bf2f(k8[4]) * v1.x * (float)w8[4] + bf2f(k8[5]) * v1.y * (float)w8[5] +
                 bf2f(k8[6]) * v1.z * (float)w8[6] + bf2f(k8[7]) * v1.w * (float)w8[7]);
  }
  #pragma unroll
  for (int s = 1; s < 64; s <<= 1) acc += __shfl_xor(acc, s);
  __syncthreads();
  if ((t & 63) == 0) scr[t >> 6] = acc;
  __syncthreads();
  if (t == 0) {
    float tot = 0.0f;
    #pragma unroll
    for (int w = 0; w < 16; ++w) tot += scr[w];
    atomicAdd(out, 2.5e-4f * tot);   // 0.001 * mean over 4 batches
  }
}

// ----------------------------------------------------------------- launch ---
extern "C" void kernel_launch(void* const* d_in, const int* in_sizes, int n_in,
                              void* d_out, int out_size, void* d_ws, size_t ws_size,
                              hipStream_t stream) {
  const float* ys = (const float*)d_in[0];
  const float* yt = (const float*)d_in[1];
  half_t* ps = (half_t*)d_ws;                    // 4*256*512 fp16 = 1 MiB
  half_t* pt = ps + (size_t)NB * NN * ND;        // 1 MiB
  half_t* W  = pt + (size_t)NB * NN * ND;        // 4*256*256 fp16 = 512 KiB
  float* out = (float*)d_out;

  softmax_k<<<2 * NB * NN, 256, 0, stream>>>(ys, yt, ps, pt, out);
  cost_k<<<dim3(8, 8, NB), 256, 0, stream>>>(ps, pt, W);
  sink_k<<<NB, 1024, 0, stream>>>(W, out);
}